// Round 7
// baseline (297.818 us; speedup 1.0000x reference)
//
#include <hip/hip_runtime.h>
#include <hip/hip_bf16.h>

#define NBATCH 2048
#define SEQL   128
#define EMB    32
#define NCODE  10

// flat output offsets (f32 elements)
#define OFF_LOG  0
#define OFF_PUZ  33554432
#define OFF_FEAT 35397632
#define OFF_Q    153362432
#define OFF_LOSS 271327232

// f32 packed-weight offsets in d_ws (float elements)
#define WP_W1   0        // [32i][3k][64o]
#define WP_W2   6144     // [64i][3k][64o]
#define WP_W3   18432    // [64i][3k][64o]
#define WP_F32_END 30720 // = 122880 bytes

// bf16 packed-weight offsets (ushort elements, base = d_ws + 122880B)
#define WH_W6   0        // [64o][200] k=kk*64+i (192 valid)
#define WH_W7E  12800    // [64o][136] k=kb*64+i; kb0:m=1, kb1:m=3
#define WH_W7O  21504    // [64o][136] kb0:m=0, kb1:m=2
#define WH_W8E  30208    // [32o][136] kb0:m=1, kb1:m=3
#define WH_W8O  34560    // [32o][136] kb0:m=0, kb1:m=2
#define WH_OW   38912    // [128v][40] e (32 valid)
#define WH_END  44032
#define WS_LOSS_BYTES 210944   // loss partials f32 [2048]

typedef __attribute__((ext_vector_type(8))) short short8v;
typedef __attribute__((ext_vector_type(4))) float f32x4;

static __device__ __forceinline__ unsigned short f2bfu(float f) {
    __hip_bfloat16 h = __float2bfloat16(f);
    unsigned short u; __builtin_memcpy(&u, &h, 2); return u;
}

static __device__ __forceinline__ f32x4 mfma16(short8v a, short8v b, f32x4 c) {
    return __builtin_amdgcn_mfma_f32_16x16x32_bf16(a, b, c, 0, 0, 0);
}

__global__ void prep_weights(const float* __restrict__ w1, const float* __restrict__ w2,
                             const float* __restrict__ w3, const float* __restrict__ dw1,
                             const float* __restrict__ dw2, const float* __restrict__ dw3,
                             const float* __restrict__ ow,
                             float* __restrict__ wp, unsigned short* __restrict__ wph)
{
    int idx = blockIdx.x * 256 + threadIdx.x;
    if (idx < 6144) {                       // w1p[i][k][o] <- w1[o][i][k]
        int o = idx & 63, r = idx >> 6, kk = r % 3, i = r / 3;
        wp[WP_W1 + idx] = w1[(o * 32 + i) * 3 + kk];
    } else if (idx < 18432) {               // w2p
        int t = idx - 6144;
        int o = t & 63, r = t >> 6, kk = r % 3, i = r / 3;
        wp[WP_W2 + t] = w2[(o * 64 + i) * 3 + kk];
    } else if (idx < 30720) {               // w3p
        int t = idx - 18432;
        int o = t & 63, r = t >> 6, kk = r % 3, i = r / 3;
        wp[WP_W3 + t] = w3[(o * 64 + i) * 3 + kk];
    } else if (idx < 30720 + WH_END) {      // bf16 packs
        int t = idx - 30720;
        float v = 0.f;
        if (t < WH_W7E) {                           // W6: convT1
            int o = t / 200, k = t % 200;
            if (k < 192) v = dw1[((k & 63) * 64 + o) * 3 + (k >> 6)];
        } else if (t < WH_W7O) {                    // W7E
            int s = t - WH_W7E; int o = s / 136, k = s % 136;
            if (k < 128) v = dw2[((k & 63) * 64 + o) * 4 + ((k >> 6) ? 3 : 1)];
        } else if (t < WH_W8E) {                    // W7O
            int s = t - WH_W7O; int o = s / 136, k = s % 136;
            if (k < 128) v = dw2[((k & 63) * 64 + o) * 4 + ((k >> 6) ? 2 : 0)];
        } else if (t < WH_W8O) {                    // W8E
            int s = t - WH_W8E; int o = s / 136, k = s % 136;
            if (k < 128) v = dw3[((k & 63) * 32 + o) * 4 + ((k >> 6) ? 3 : 1)];
        } else if (t < WH_OW) {                     // W8O
            int s = t - WH_W8O; int o = s / 136, k = s % 136;
            if (k < 128) v = dw3[((k & 63) * 32 + o) * 4 + ((k >> 6) ? 2 : 0)];
        } else {                                    // OW
            int s = t - WH_OW; int vv = s / 40, e = s % 40;
            if (e < 32) v = ow[vv * 32 + e];
        }
        wph[t] = f2bfu(v);
    }
}

// LDS layout (bytes into sm[40000]) — full liveness audit:
//  xs   [32][130] @0      16640  P0-P1
//  h1   [64][66]  @16640  16896  P1-P2   (ends 33536)
//  h2   [64][34]  @0      8704   P2-P3   (xs dead)
//  h3   [64][30]  @16640  7680   P3-P5   (h1 dead; ends 24320)
//  cbs  [10][64]  @24320  2560   P3-P5
//  codes[30]      @26880  128    P4-P5   (puzzles written in P5)
//  encf [30][64]  @0      7680   P5-END  (h2 dead)
//  qf   [30][64]  @7680   7680   P5-END  (ends 15360)
//  Xq   [34][72]  @27008  4896   P5-P6   (ends 31904)
//  X7   [34][72]  @15360  4896   P6-P7   (ends 20256; h3 dead)
//  X8   [66][72]  @20256  9504   P7-P8   (ends 29760; cbs/codes/Xq dead)
//  Xd   [128][40] @29760  10240  P8-P9   (ends 40000)
//  END: feat/q stores read encf/qf (0..15360 — untouched since P5)

__global__ __launch_bounds__(256, 4)
void vae_fused(const int* __restrict__ tidx, const float* __restrict__ emb,
               const float* __restrict__ b1, const float* __restrict__ b2,
               const float* __restrict__ b3, const float* __restrict__ cb,
               const float* __restrict__ db1, const float* __restrict__ db2,
               const float* __restrict__ db3, const float* __restrict__ ob,
               const float* __restrict__ wp, const unsigned short* __restrict__ wph,
               float* __restrict__ out, float* __restrict__ loss_part)
{
    __shared__ __align__(16) char sm[40000];
    float* xs   = (float*)(sm);            // [32][130]
    float* h1   = (float*)(sm + 16640);    // [64][66]
    float* h2   = (float*)(sm);            // [64][34]
    float* h3   = (float*)(sm + 16640);    // [64][30]
    float* cbs  = (float*)(sm + 24320);    // [10][64]
    int*   codes= (int*)  (sm + 26880);    // [30]
    float* encf = (float*)(sm);            // [30][64]
    float* qf   = (float*)(sm + 7680);     // [30][64]
    unsigned short* Xq = (unsigned short*)(sm + 27008); // [34][72]
    unsigned short* X7 = (unsigned short*)(sm + 15360); // [34][72]
    unsigned short* X8 = (unsigned short*)(sm + 20256); // [66][72]
    unsigned short* Xd = (unsigned short*)(sm + 29760); // [128][40]

    const int b   = blockIdx.x;
    const int tid = threadIdx.x;
    const int* ti = tidx + b * SEQL;

    const int lane = tid & 63;
    const int wid  = tid >> 6;
    const int lr = lane & 15, lk8 = (lane >> 4) * 8;
    const int rquad = (lane >> 4) * 4;

    // ---------- P0: coalesced embedding gather  xs[e][1+l] = emb[ti[l]][e] ----------
    for (int v = tid; v < EMB * SEQL; v += 256) {
        int l = v >> 5, e = v & 31;
        xs[e * 130 + 1 + l] = emb[ti[l] * EMB + e];
    }
    if (tid < 32) xs[tid * 130] = 0.f;
    __syncthreads();

    // ---------- P1: conv1 32->64ch, L128->64, k3 s2 p1, relu (R3-pass text) ----------
    {
        const int og = tid >> 4, o0 = og * 4;
        const int ln = tid & 15;
        float acc[4][4];
        #pragma unroll
        for (int a = 0; a < 4; a++) {
            float bb = b1[o0 + a];
            #pragma unroll
            for (int c = 0; c < 4; c++) acc[a][c] = bb;
        }
        const float4* w1v = (const float4*)(wp + WP_W1);
        #pragma unroll 2
        for (int i = 0; i < 32; i++) {
            #pragma unroll
            for (int kk = 0; kk < 3; kk++) {
                float4 wv4 = w1v[(i * 3 + kk) * 16 + og];
                const float* wv = (const float*)&wv4;
                #pragma unroll
                for (int c = 0; c < 4; c++) {
                    float xv = xs[i * 130 + 2 * (ln + 16 * c) + kk];
                    #pragma unroll
                    for (int a = 0; a < 4; a++)
                        acc[a][c] = fmaf(wv[a], xv, acc[a][c]);
                }
            }
        }
        #pragma unroll
        for (int a = 0; a < 4; a++)
            #pragma unroll
            for (int c = 0; c < 4; c++)
                h1[(o0 + a) * 66 + 1 + ln + 16 * c] = fmaxf(acc[a][c], 0.f);
        if (tid < 64) h1[tid * 66] = 0.f;
    }
    __syncthreads();

    // ---------- P2: conv2 64->64ch, 64->32, k3 s2 p1, relu (R3-pass text) ----------
    {
        const int og = tid >> 3, o0 = og * 2;
        const int ln = tid & 7;
        float acc[2][4];
        #pragma unroll
        for (int a = 0; a < 2; a++) {
            float bb = b2[o0 + a];
            #pragma unroll
            for (int c = 0; c < 4; c++) acc[a][c] = bb;
        }
        const float2* w2v = (const float2*)(wp + WP_W2);
        #pragma unroll 2
        for (int i = 0; i < 64; i++) {
            #pragma unroll
            for (int kk = 0; kk < 3; kk++) {
                float2 wv = w2v[(i * 3 + kk) * 32 + og];
                #pragma unroll
                for (int c = 0; c < 4; c++) {
                    float xv = h1[i * 66 + 2 * (ln + 8 * c) + kk];
                    acc[0][c] = fmaf(wv.x, xv, acc[0][c]);
                    acc[1][c] = fmaf(wv.y, xv, acc[1][c]);
                }
            }
        }
        #pragma unroll
        for (int a = 0; a < 2; a++)
            #pragma unroll
            for (int c = 0; c < 4; c++)
                h2[(o0 + a) * 34 + ln + 8 * c] = fmaxf(acc[a][c], 0.f);
        if (tid < 64) { h2[tid * 34 + 32] = 0.f; h2[tid * 34 + 33] = 0.f; }
    }
    __syncthreads();

    // ---------- P3: conv3 64->64ch, 32->30, k3 s1 p0 (no relu); codebook (R3-pass text) ----------
    {
        const int og = tid >> 3, o0 = og * 2;
        const int ln = tid & 7;
        float acc[2][4];
        #pragma unroll
        for (int a = 0; a < 2; a++) {
            float bb = b3[o0 + a];
            #pragma unroll
            for (int c = 0; c < 4; c++) acc[a][c] = bb;
        }
        const float2* w3v = (const float2*)(wp + WP_W3);
        #pragma unroll 2
        for (int i = 0; i < 64; i++) {
            #pragma unroll
            for (int kk = 0; kk < 3; kk++) {
                float2 wv = w3v[(i * 3 + kk) * 32 + og];
                #pragma unroll
                for (int c = 0; c < 4; c++) {
                    float xv = h2[i * 34 + ln + 8 * c + kk];
                    acc[0][c] = fmaf(wv.x, xv, acc[0][c]);
                    acc[1][c] = fmaf(wv.y, xv, acc[1][c]);
                }
            }
        }
        #pragma unroll
        for (int a = 0; a < 2; a++)
            #pragma unroll
            for (int c = 0; c < 4; c++) {
                int col = ln + 8 * c;
                if (col < 30) h3[(o0 + a) * 30 + col] = acc[a][c];
            }
        for (int v = tid; v < NCODE * 64; v += 256) cbs[v] = cb[v];
    }
    __syncthreads();

    // ---------- P4: VQ argmin (f64, exact for f32 inputs) ----------
    {
        float myd2 = 0.f;
        if (tid < 30) {
            const int i = tid;
            double d2[NCODE];
            #pragma unroll
            for (int c = 0; c < NCODE; c++) d2[c] = 0.0;
            for (int d = 0; d < 64; d++) {
                double v = (double)h3[d * 30 + i];
                #pragma unroll
                for (int c = 0; c < NCODE; c++) {
                    double df = v - (double)cbs[c * 64 + d];
                    d2[c] += df * df;
                }
            }
            int best = 0; double bd = d2[0];
            #pragma unroll
            for (int c = 1; c < NCODE; c++) if (d2[c] < bd) { bd = d2[c]; best = c; }
            codes[i] = best;
            myd2 = (float)bd;
        }
        float s = myd2;
        #pragma unroll
        for (int off = 32; off; off >>= 1) s += __shfl_down(s, off);
        if (tid == 0) loss_part[b] = s;
    }
    __syncthreads();

    // ---------- P5: encf/qf f32 (persist to END), puzzles, Xq bf16 ----------
    {
        for (int v = tid; v < 30 * 64; v += 256) {
            int i = v >> 6, d = v & 63;
            float fv = h3[d * 30 + i];
            float qv = cbs[codes[i] * 64 + d];
            float sv = fv + (qv - fv);      // straight-through value
            encf[v] = fv;
            qf[v]   = sv;
            Xq[(i + 2) * 72 + d] = f2bfu(sv);
        }
        for (int v = tid; v < 900; v += 256)
            out[OFF_PUZ + b * 900 + v] = (float)codes[v / 30];
        for (int v = tid; v < 4 * 72; v += 256) {
            int rr = v / 72, c = v % 72;
            int row = (rr < 2) ? rr : rr + 30;      // rows 0,1,32,33
            Xq[row * 72 + c] = 0;
        }
    }
    __syncthreads();

    // ---------- P6: MFMA convT1 (K=192) -> X7 ----------
    {
        for (int v = tid; v < 2 * 72; v += 256) {
            int rr = v / 72, c = v % 72;
            X7[(rr ? 33 : 0) * 72 + c] = 0;
        }
        const unsigned short* w6p = wph + WH_W6;
        #pragma unroll
        for (int q = 0; q < 2; q++) {
            int T = wid * 2 + q;
            int m0 = (T >> 2) * 16, o0 = (T & 3) * 16;
            f32x4 acc;
            float bias = db1[o0 + lr];
            acc[0] = acc[1] = acc[2] = acc[3] = bias;
            #pragma unroll
            for (int kk = 0; kk < 3; kk++)
                #pragma unroll
                for (int k2 = 0; k2 < 2; k2++) {
                    short8v a = *(const short8v*)&Xq[(m0 + lr - kk + 2) * 72 + k2 * 32 + lk8];
                    short8v w = *(const short8v*)&w6p[(o0 + lr) * 200 + kk * 64 + k2 * 32 + lk8];
                    acc = mfma16(a, w, acc);
                }
            #pragma unroll
            for (int r = 0; r < 4; r++) {
                int t = m0 + rquad + r;
                X7[(t + 1) * 72 + o0 + lr] = f2bfu(fmaxf(acc[r], 0.f));
            }
        }
    }
    __syncthreads();

    // ---------- P7: MFMA convT2 (parity GEMMs, K=128) -> X8 ----------
    {
        for (int v = tid; v < 2 * 72; v += 256) {
            int rr = v / 72, c = v % 72;
            X8[(rr ? 65 : 0) * 72 + c] = 0;
        }
        #pragma unroll
        for (int q = 0; q < 4; q++) {
            int T = wid * 4 + q;            // 0..15
            int p  = T >> 3;
            int m0 = ((T >> 2) & 1) * 16, o0 = (T & 3) * 16;
            const unsigned short* wb = wph + (p ? WH_W7O : WH_W7E);
            f32x4 acc;
            float bias = db2[o0 + lr];
            acc[0] = acc[1] = acc[2] = acc[3] = bias;
            int rb0 = p ? 2 : 1, rb1 = p ? 1 : 0;
            #pragma unroll
            for (int kb = 0; kb < 2; kb++) {
                int rbase = kb ? rb1 : rb0;
                #pragma unroll
                for (int k2 = 0; k2 < 2; k2++) {
                    short8v a = *(const short8v*)&X7[(m0 + lr + rbase) * 72 + k2 * 32 + lk8];
                    short8v w = *(const short8v*)&wb[(o0 + lr) * 136 + kb * 64 + k2 * 32 + lk8];
                    acc = mfma16(a, w, acc);
                }
            }
            #pragma unroll
            for (int r = 0; r < 4; r++) {
                int t = 2 * (m0 + rquad + r) + p;
                X8[(t + 1) * 72 + o0 + lr] = f2bfu(fmaxf(acc[r], 0.f));
            }
        }
    }
    __syncthreads();

    // ---------- P8: MFMA convT3 (parity GEMMs, K=128) -> Xd [l][e] ----------
    {
        #pragma unroll
        for (int q = 0; q < 4; q++) {
            int T = wid * 4 + q;            // 0..15
            int p  = T >> 3;
            int m0 = ((T >> 1) & 3) * 16, o0 = (T & 1) * 16;
            const unsigned short* wb = wph + (p ? WH_W8O : WH_W8E);
            f32x4 acc;
            float bias = db3[o0 + lr];
            acc[0] = acc[1] = acc[2] = acc[3] = bias;
            int rb0 = p ? 2 : 1, rb1 = p ? 1 : 0;
            #pragma unroll
            for (int kb = 0; kb < 2; kb++) {
                int rbase = kb ? rb1 : rb0;
                #pragma unroll
                for (int k2 = 0; k2 < 2; k2++) {
                    short8v a = *(const short8v*)&X8[(m0 + lr + rbase) * 72 + k2 * 32 + lk8];
                    short8v w = *(const short8v*)&wb[(o0 + lr) * 136 + kb * 64 + k2 * 32 + lk8];
                    acc = mfma16(a, w, acc);
                }
            }
            #pragma unroll
            for (int r = 0; r < 4; r++) {
                int l = 2 * (m0 + rquad + r) + p;
                Xd[l * 40 + o0 + lr] = f2bfu(acc[r]);   // no relu
            }
        }
    }
    __syncthreads();

    // ---------- P9: MFMA logits GEMM [128l][128v][K=32] -> global ----------
    {
        const unsigned short* owp = wph + WH_OW;
        float* outL = out + OFF_LOG + b * 16384;
        #pragma unroll 4
        for (int q = 0; q < 16; q++) {
            int T = wid * 16 + q;
            int m0 = (T >> 3) * 16, n0 = (T & 7) * 16;
            f32x4 acc;
            float bias = ob[n0 + lr];
            acc[0] = acc[1] = acc[2] = acc[3] = bias;
            short8v a = *(const short8v*)&Xd[(m0 + lr) * 40 + lk8];
            short8v w = *(const short8v*)&owp[(n0 + lr) * 40 + lk8];
            acc = mfma16(a, w, acc);
            #pragma unroll
            for (int r = 0; r < 4; r++)
                outL[(m0 + rquad + r) * 128 + n0 + lr] = acc[r];
        }
    }

    // ---------- P10 (no barrier): features/quantized writes from encf/qf ----------
    // encf/qf untouched since P5; stores drain at kernel end, overlapping the
    // next resident block's compute instead of stalling this block's barriers.
    {
        float4* dF = ((float4*)(out + OFF_FEAT)) + b * 14400;
        float4* dQ = ((float4*)(out + OFF_Q))    + b * 14400;
        const float4* sE = (const float4*)encf;
        const float4* sQ = (const float4*)qf;
        for (int v = tid; v < 14400; v += 256) {
            int row = v >> 4, part = v & 15;   // row = i*30+j, part = d/4
            int i = row / 30;
            dF[v] = sE[i * 16 + part];
            dQ[v] = sQ[i * 16 + part];
        }
    }
}

__global__ void loss_final(const float* __restrict__ part, float* __restrict__ out) {
    __shared__ float red[4];
    const int tid = threadIdx.x;
    float s = 0.f;
    for (int k = tid; k < NBATCH; k += 256) s += part[k];
    #pragma unroll
    for (int off = 32; off; off >>= 1) s += __shfl_down(s, off);
    if ((tid & 63) == 0) red[tid >> 6] = s;
    __syncthreads();
    if (tid == 0) {
        float t = red[0] + red[1] + red[2] + red[3];
        out[OFF_LOSS] = 1.25f * t / 3932160.0f;
    }
}

extern "C" void kernel_launch(void* const* d_in, const int* in_sizes, int n_in,
                              void* d_out, int out_size, void* d_ws, size_t ws_size,
                              hipStream_t stream) {
    const int*   tidx = (const int*)  d_in[0];
    const float* emb  = (const float*)d_in[1];
    const float* w1   = (const float*)d_in[2];
    const float* b1   = (const float*)d_in[3];
    const float* w2   = (const float*)d_in[4];
    const float* b2   = (const float*)d_in[5];
    const float* w3   = (const float*)d_in[6];
    const float* b3   = (const float*)d_in[7];
    const float* cb   = (const float*)d_in[8];
    const float* dw1  = (const float*)d_in[9];
    const float* db1  = (const float*)d_in[10];
    const float* dw2  = (const float*)d_in[11];
    const float* db2  = (const float*)d_in[12];
    const float* dw3  = (const float*)d_in[13];
    const float* db3  = (const float*)d_in[14];
    const float* ow   = (const float*)d_in[15];
    const float* ob   = (const float*)d_in[16];
    float* out = (float*)d_out;
    float* wp  = (float*)d_ws;                                   // f32 packs
    unsigned short* wph = (unsigned short*)((char*)d_ws + 122880); // bf16 packs
    float* part = (float*)((char*)d_ws + WS_LOSS_BYTES);         // [2048]

    prep_weights<<<292, 256, 0, stream>>>(w1, w2, w3, dw1, dw2, dw3, ow, wp, wph);
    vae_fused<<<NBATCH, 256, 0, stream>>>(tidx, emb, b1, b2, b3, cb,
                                          db1, db2, db3, ob, wp, wph,
                                          out, part);
    loss_final<<<1, 256, 0, stream>>>(part, out);
}

// Round 8
// 287.464 us; speedup vs baseline: 1.0360x; 1.0360x over previous
//
#include <hip/hip_runtime.h>
#include <hip/hip_bf16.h>

#define NBATCH 2048
#define SEQL   128
#define EMB    32
#define NCODE  10

// flat output offsets (f32 elements)
#define OFF_LOG  0
#define OFF_PUZ  33554432
#define OFF_FEAT 35397632
#define OFF_Q    153362432
#define OFF_LOSS 271327232

// f32 packed-weight offsets in d_ws (float elements)
#define WP_W1   0        // [32i][3k][64o]
#define WP_W2   6144     // [64i][3k][64o]
#define WP_W3   18432    // [64i][3k][64o]
#define WP_F32_END 30720 // = 122880 bytes

// bf16 packed-weight offsets (ushort elements, base = d_ws + 122880B)
#define WH_W6   0        // [64o][200] k=kk*64+i (192 valid)
#define WH_W7E  12800    // [64o][136] k=kb*64+i; kb0:m=1, kb1:m=3
#define WH_W7O  21504    // [64o][136] kb0:m=0, kb1:m=2
#define WH_W8E  30208    // [32o][136] kb0:m=1, kb1:m=3
#define WH_W8O  34560    // [32o][136] kb0:m=0, kb1:m=2
#define WH_OW   38912    // [128v][40] e (32 valid)
#define WH_END  44032
#define WS_LOSS_BYTES 210944   // loss partials f32 [2048]

typedef __attribute__((ext_vector_type(8))) short short8v;
typedef __attribute__((ext_vector_type(4))) float f32x4;

static __device__ __forceinline__ unsigned short f2bfu(float f) {
    __hip_bfloat16 h = __float2bfloat16(f);
    unsigned short u; __builtin_memcpy(&u, &h, 2); return u;
}

static __device__ __forceinline__ f32x4 mfma16(short8v a, short8v b, f32x4 c) {
    return __builtin_amdgcn_mfma_f32_16x16x32_bf16(a, b, c, 0, 0, 0);
}

__global__ void prep_weights(const float* __restrict__ w1, const float* __restrict__ w2,
                             const float* __restrict__ w3, const float* __restrict__ dw1,
                             const float* __restrict__ dw2, const float* __restrict__ dw3,
                             const float* __restrict__ ow,
                             float* __restrict__ wp, unsigned short* __restrict__ wph)
{
    int idx = blockIdx.x * 256 + threadIdx.x;
    if (idx < 6144) {                       // w1p[i][k][o] <- w1[o][i][k]
        int o = idx & 63, r = idx >> 6, kk = r % 3, i = r / 3;
        wp[WP_W1 + idx] = w1[(o * 32 + i) * 3 + kk];
    } else if (idx < 18432) {               // w2p
        int t = idx - 6144;
        int o = t & 63, r = t >> 6, kk = r % 3, i = r / 3;
        wp[WP_W2 + t] = w2[(o * 64 + i) * 3 + kk];
    } else if (idx < 30720) {               // w3p
        int t = idx - 18432;
        int o = t & 63, r = t >> 6, kk = r % 3, i = r / 3;
        wp[WP_W3 + t] = w3[(o * 64 + i) * 3 + kk];
    } else if (idx < 30720 + WH_END) {      // bf16 packs
        int t = idx - 30720;
        float v = 0.f;
        if (t < WH_W7E) {                           // W6: convT1
            int o = t / 200, k = t % 200;
            if (k < 192) v = dw1[((k & 63) * 64 + o) * 3 + (k >> 6)];
        } else if (t < WH_W7O) {                    // W7E
            int s = t - WH_W7E; int o = s / 136, k = s % 136;
            if (k < 128) v = dw2[((k & 63) * 64 + o) * 4 + ((k >> 6) ? 3 : 1)];
        } else if (t < WH_W8E) {                    // W7O
            int s = t - WH_W7O; int o = s / 136, k = s % 136;
            if (k < 128) v = dw2[((k & 63) * 64 + o) * 4 + ((k >> 6) ? 2 : 0)];
        } else if (t < WH_W8O) {                    // W8E
            int s = t - WH_W8E; int o = s / 136, k = s % 136;
            if (k < 128) v = dw3[((k & 63) * 32 + o) * 4 + ((k >> 6) ? 3 : 1)];
        } else if (t < WH_OW) {                     // W8O
            int s = t - WH_W8O; int o = s / 136, k = s % 136;
            if (k < 128) v = dw3[((k & 63) * 32 + o) * 4 + ((k >> 6) ? 2 : 0)];
        } else {                                    // OW
            int s = t - WH_OW; int vv = s / 40, e = s % 40;
            if (e < 32) v = ow[vv * 32 + e];
        }
        wph[t] = f2bfu(v);
    }
}

// LDS layout (bytes into sm[40000]) — liveness identical to R7 (passed):
//  xs   [32][130] @0      16640  P0-P1
//  h1   [64][66]  @16640  16896  P1-P2
//  h2   [64][34]  @0      8704   P2-P3
//  h3   [64][30]  @16640  7680   P3-P5
//  cbs  [10][64]  @24320  2560   P3-P5
//  codes[30]      @26880  128    P4-P5
//  encf [30][64]  @0      7680   P5-P9  (read by write-chunks in P6..P9)
//  qf   [30][64]  @7680   7680   P5-P9
//  Xq   [34][72]  @27008  4896   P5-P6
//  X7   [34][72]  @15360  4896   P6-P7
//  X8   [66][72]  @20256  9504   P7-P8
//  Xd   [128][40] @29760  10240  P8-P9

__global__ __launch_bounds__(256, 4)
void vae_fused(const int* __restrict__ tidx, const float* __restrict__ emb,
               const float* __restrict__ b1, const float* __restrict__ b2,
               const float* __restrict__ b3, const float* __restrict__ cb,
               const float* __restrict__ db1, const float* __restrict__ db2,
               const float* __restrict__ db3, const float* __restrict__ ob,
               const float* __restrict__ wp, const unsigned short* __restrict__ wph,
               float* __restrict__ out, float* __restrict__ loss_part)
{
    __shared__ __align__(16) char sm[40000];
    float* xs   = (float*)(sm);            // [32][130]
    float* h1   = (float*)(sm + 16640);    // [64][66]
    float* h2   = (float*)(sm);            // [64][34]
    float* h3   = (float*)(sm + 16640);    // [64][30]
    float* cbs  = (float*)(sm + 24320);    // [10][64]
    int*   codes= (int*)  (sm + 26880);    // [30]
    float* encf = (float*)(sm);            // [30][64]
    float* qf   = (float*)(sm + 7680);     // [30][64]
    unsigned short* Xq = (unsigned short*)(sm + 27008); // [34][72]
    unsigned short* X7 = (unsigned short*)(sm + 15360); // [34][72]
    unsigned short* X8 = (unsigned short*)(sm + 20256); // [66][72]
    unsigned short* Xd = (unsigned short*)(sm + 29760); // [128][40]

    const int b   = blockIdx.x;
    const int tid = threadIdx.x;
    const int* ti = tidx + b * SEQL;

    const int lane = tid & 63;
    const int wid  = tid >> 6;
    const int lr = lane & 15, lk8 = (lane >> 4) * 8;
    const int rquad = (lane >> 4) * 4;

    float4* dF = ((float4*)(out + OFF_FEAT)) + b * 14400;
    float4* dQ = ((float4*)(out + OFF_Q))    + b * 14400;
    const float4* sE = (const float4*)encf;
    const float4* sQ = (const float4*)qf;

    // ---------- P0: coalesced embedding gather  xs[e][1+l] = emb[ti[l]][e] ----------
    for (int v = tid; v < EMB * SEQL; v += 256) {
        int l = v >> 5, e = v & 31;
        xs[e * 130 + 1 + l] = emb[ti[l] * EMB + e];
    }
    if (tid < 32) xs[tid * 130] = 0.f;
    __syncthreads();

    // ---------- P1: conv1 32->64ch, L128->64, k3 s2 p1, relu (FROZEN text) ----------
    {
        const int og = tid >> 4, o0 = og * 4;
        const int ln = tid & 15;
        float acc[4][4];
        #pragma unroll
        for (int a = 0; a < 4; a++) {
            float bb = b1[o0 + a];
            #pragma unroll
            for (int c = 0; c < 4; c++) acc[a][c] = bb;
        }
        const float4* w1v = (const float4*)(wp + WP_W1);
        #pragma unroll 2
        for (int i = 0; i < 32; i++) {
            #pragma unroll
            for (int kk = 0; kk < 3; kk++) {
                float4 wv4 = w1v[(i * 3 + kk) * 16 + og];
                const float* wv = (const float*)&wv4;
                #pragma unroll
                for (int c = 0; c < 4; c++) {
                    float xv = xs[i * 130 + 2 * (ln + 16 * c) + kk];
                    #pragma unroll
                    for (int a = 0; a < 4; a++)
                        acc[a][c] = fmaf(wv[a], xv, acc[a][c]);
                }
            }
        }
        #pragma unroll
        for (int a = 0; a < 4; a++)
            #pragma unroll
            for (int c = 0; c < 4; c++)
                h1[(o0 + a) * 66 + 1 + ln + 16 * c] = fmaxf(acc[a][c], 0.f);
        if (tid < 64) h1[tid * 66] = 0.f;
    }
    __syncthreads();

    // ---------- P2: conv2 64->64ch, 64->32, k3 s2 p1, relu (FROZEN text) ----------
    {
        const int og = tid >> 3, o0 = og * 2;
        const int ln = tid & 7;
        float acc[2][4];
        #pragma unroll
        for (int a = 0; a < 2; a++) {
            float bb = b2[o0 + a];
            #pragma unroll
            for (int c = 0; c < 4; c++) acc[a][c] = bb;
        }
        const float2* w2v = (const float2*)(wp + WP_W2);
        #pragma unroll 2
        for (int i = 0; i < 64; i++) {
            #pragma unroll
            for (int kk = 0; kk < 3; kk++) {
                float2 wv = w2v[(i * 3 + kk) * 32 + og];
                #pragma unroll
                for (int c = 0; c < 4; c++) {
                    float xv = h1[i * 66 + 2 * (ln + 8 * c) + kk];
                    acc[0][c] = fmaf(wv.x, xv, acc[0][c]);
                    acc[1][c] = fmaf(wv.y, xv, acc[1][c]);
                }
            }
        }
        #pragma unroll
        for (int a = 0; a < 2; a++)
            #pragma unroll
            for (int c = 0; c < 4; c++)
                h2[(o0 + a) * 34 + ln + 8 * c] = fmaxf(acc[a][c], 0.f);
        if (tid < 64) { h2[tid * 34 + 32] = 0.f; h2[tid * 34 + 33] = 0.f; }
    }
    __syncthreads();

    // ---------- P3: conv3 64->64ch, 32->30, k3 s1 p0; codebook (FROZEN text) ----------
    {
        const int og = tid >> 3, o0 = og * 2;
        const int ln = tid & 7;
        float acc[2][4];
        #pragma unroll
        for (int a = 0; a < 2; a++) {
            float bb = b3[o0 + a];
            #pragma unroll
            for (int c = 0; c < 4; c++) acc[a][c] = bb;
        }
        const float2* w3v = (const float2*)(wp + WP_W3);
        #pragma unroll 2
        for (int i = 0; i < 64; i++) {
            #pragma unroll
            for (int kk = 0; kk < 3; kk++) {
                float2 wv = w3v[(i * 3 + kk) * 32 + og];
                #pragma unroll
                for (int c = 0; c < 4; c++) {
                    float xv = h2[i * 34 + ln + 8 * c + kk];
                    acc[0][c] = fmaf(wv.x, xv, acc[0][c]);
                    acc[1][c] = fmaf(wv.y, xv, acc[1][c]);
                }
            }
        }
        #pragma unroll
        for (int a = 0; a < 2; a++)
            #pragma unroll
            for (int c = 0; c < 4; c++) {
                int col = ln + 8 * c;
                if (col < 30) h3[(o0 + a) * 30 + col] = acc[a][c];
            }
        for (int v = tid; v < NCODE * 64; v += 256) cbs[v] = cb[v];
    }
    __syncthreads();

    // ---------- P4: VQ argmin (f64, exact for f32 inputs) ----------
    {
        float myd2 = 0.f;
        if (tid < 30) {
            const int i = tid;
            double d2[NCODE];
            #pragma unroll
            for (int c = 0; c < NCODE; c++) d2[c] = 0.0;
            for (int d = 0; d < 64; d++) {
                double v = (double)h3[d * 30 + i];
                #pragma unroll
                for (int c = 0; c < NCODE; c++) {
                    double df = v - (double)cbs[c * 64 + d];
                    d2[c] += df * df;
                }
            }
            int best = 0; double bd = d2[0];
            #pragma unroll
            for (int c = 1; c < NCODE; c++) if (d2[c] < bd) { bd = d2[c]; best = c; }
            codes[i] = best;
            myd2 = (float)bd;
        }
        float s = myd2;
        #pragma unroll
        for (int off = 32; off; off >>= 1) s += __shfl_down(s, off);
        if (tid == 0) loss_part[b] = s;
    }
    __syncthreads();

    // ---------- P5: encf/qf f32 (persist to P9), puzzles, Xq bf16 ----------
    {
        for (int v = tid; v < 30 * 64; v += 256) {
            int i = v >> 6, d = v & 63;
            float fv = h3[d * 30 + i];
            float qv = cbs[codes[i] * 64 + d];
            float sv = fv + (qv - fv);      // straight-through value
            encf[v] = fv;
            qf[v]   = sv;
            Xq[(i + 2) * 72 + d] = f2bfu(sv);
        }
        for (int v = tid; v < 900; v += 256)
            out[OFF_PUZ + b * 900 + v] = (float)codes[v / 30];
        for (int v = tid; v < 4 * 72; v += 256) {
            int rr = v / 72, c = v % 72;
            int row = (rr < 2) ? rr : rr + 30;      // rows 0,1,32,33
            Xq[row * 72 + c] = 0;
        }
    }
    __syncthreads();

    // ---------- P6: write chunk 0 + MFMA convT1 (K=192) -> X7 ----------
    {
        for (int v = tid; v < 3600; v += 256) {        // chunk 0: drain overlaps MFMA
            int row = v >> 4, part = v & 15;
            int i = row / 30;
            dF[v] = sE[i * 16 + part];
            dQ[v] = sQ[i * 16 + part];
        }
        for (int v = tid; v < 2 * 72; v += 256) {
            int rr = v / 72, c = v % 72;
            X7[(rr ? 33 : 0) * 72 + c] = 0;
        }
        const unsigned short* w6p = wph + WH_W6;
        #pragma unroll
        for (int q = 0; q < 2; q++) {
            int T = wid * 2 + q;
            int m0 = (T >> 2) * 16, o0 = (T & 3) * 16;
            f32x4 acc;
            float bias = db1[o0 + lr];
            acc[0] = acc[1] = acc[2] = acc[3] = bias;
            #pragma unroll
            for (int kk = 0; kk < 3; kk++)
                #pragma unroll
                for (int k2 = 0; k2 < 2; k2++) {
                    short8v a = *(const short8v*)&Xq[(m0 + lr - kk + 2) * 72 + k2 * 32 + lk8];
                    short8v w = *(const short8v*)&w6p[(o0 + lr) * 200 + kk * 64 + k2 * 32 + lk8];
                    acc = mfma16(a, w, acc);
                }
            #pragma unroll
            for (int r = 0; r < 4; r++) {
                int t = m0 + rquad + r;
                X7[(t + 1) * 72 + o0 + lr] = f2bfu(fmaxf(acc[r], 0.f));
            }
        }
    }
    __syncthreads();

    // ---------- P7: write chunk 1 + MFMA convT2 (parity GEMMs, K=128) -> X8 ----------
    {
        for (int v = 3600 + tid; v < 7200; v += 256) { // chunk 1
            int row = v >> 4, part = v & 15;
            int i = row / 30;
            dF[v] = sE[i * 16 + part];
            dQ[v] = sQ[i * 16 + part];
        }
        for (int v = tid; v < 2 * 72; v += 256) {
            int rr = v / 72, c = v % 72;
            X8[(rr ? 65 : 0) * 72 + c] = 0;
        }
        #pragma unroll
        for (int q = 0; q < 4; q++) {
            int T = wid * 4 + q;            // 0..15
            int p  = T >> 3;
            int m0 = ((T >> 2) & 1) * 16, o0 = (T & 3) * 16;
            const unsigned short* wb = wph + (p ? WH_W7O : WH_W7E);
            f32x4 acc;
            float bias = db2[o0 + lr];
            acc[0] = acc[1] = acc[2] = acc[3] = bias;
            int rb0 = p ? 2 : 1, rb1 = p ? 1 : 0;
            #pragma unroll
            for (int kb = 0; kb < 2; kb++) {
                int rbase = kb ? rb1 : rb0;
                #pragma unroll
                for (int k2 = 0; k2 < 2; k2++) {
                    short8v a = *(const short8v*)&X7[(m0 + lr + rbase) * 72 + k2 * 32 + lk8];
                    short8v w = *(const short8v*)&wb[(o0 + lr) * 136 + kb * 64 + k2 * 32 + lk8];
                    acc = mfma16(a, w, acc);
                }
            }
            #pragma unroll
            for (int r = 0; r < 4; r++) {
                int t = 2 * (m0 + rquad + r) + p;
                X8[(t + 1) * 72 + o0 + lr] = f2bfu(fmaxf(acc[r], 0.f));
            }
        }
    }
    __syncthreads();

    // ---------- P8: write chunk 2 + MFMA convT3 (parity GEMMs, K=128) -> Xd ----------
    {
        for (int v = 7200 + tid; v < 10800; v += 256) { // chunk 2
            int row = v >> 4, part = v & 15;
            int i = row / 30;
            dF[v] = sE[i * 16 + part];
            dQ[v] = sQ[i * 16 + part];
        }
        #pragma unroll
        for (int q = 0; q < 4; q++) {
            int T = wid * 4 + q;            // 0..15
            int p  = T >> 3;
            int m0 = ((T >> 1) & 3) * 16, o0 = (T & 1) * 16;
            const unsigned short* wb = wph + (p ? WH_W8O : WH_W8E);
            f32x4 acc;
            float bias = db3[o0 + lr];
            acc[0] = acc[1] = acc[2] = acc[3] = bias;
            int rb0 = p ? 2 : 1, rb1 = p ? 1 : 0;
            #pragma unroll
            for (int kb = 0; kb < 2; kb++) {
                int rbase = kb ? rb1 : rb0;
                #pragma unroll
                for (int k2 = 0; k2 < 2; k2++) {
                    short8v a = *(const short8v*)&X8[(m0 + lr + rbase) * 72 + k2 * 32 + lk8];
                    short8v w = *(const short8v*)&wb[(o0 + lr) * 136 + kb * 64 + k2 * 32 + lk8];
                    acc = mfma16(a, w, acc);
                }
            }
            #pragma unroll
            for (int r = 0; r < 4; r++) {
                int l = 2 * (m0 + rquad + r) + p;
                Xd[l * 40 + o0 + lr] = f2bfu(acc[r]);   // no relu
            }
        }
    }
    __syncthreads();

    // ---------- P9: write chunk 3 + MFMA logits GEMM -> global (no trailing barrier) ----------
    {
        for (int v = 10800 + tid; v < 14400; v += 256) { // chunk 3 (drains at endpgm)
            int row = v >> 4, part = v & 15;
            int i = row / 30;
            dF[v] = sE[i * 16 + part];
            dQ[v] = sQ[i * 16 + part];
        }
        const unsigned short* owp = wph + WH_OW;
        float* outL = out + OFF_LOG + b * 16384;
        #pragma unroll 4
        for (int q = 0; q < 16; q++) {
            int T = wid * 16 + q;
            int m0 = (T >> 3) * 16, n0 = (T & 7) * 16;
            f32x4 acc;
            float bias = ob[n0 + lr];
            acc[0] = acc[1] = acc[2] = acc[3] = bias;
            short8v a = *(const short8v*)&Xd[(m0 + lr) * 40 + lk8];
            short8v w = *(const short8v*)&owp[(n0 + lr) * 40 + lk8];
            acc = mfma16(a, w, acc);
            #pragma unroll
            for (int r = 0; r < 4; r++)
                outL[(m0 + rquad + r) * 128 + n0 + lr] = acc[r];
        }
    }
}

__global__ void loss_final(const float* __restrict__ part, float* __restrict__ out) {
    __shared__ float red[4];
    const int tid = threadIdx.x;
    float s = 0.f;
    for (int k = tid; k < NBATCH; k += 256) s += part[k];
    #pragma unroll
    for (int off = 32; off; off >>= 1) s += __shfl_down(s, off);
    if ((tid & 63) == 0) red[tid >> 6] = s;
    __syncthreads();
    if (tid == 0) {
        float t = red[0] + red[1] + red[2] + red[3];
        out[OFF_LOSS] = 1.25f * t / 3932160.0f;
    }
}

extern "C" void kernel_launch(void* const* d_in, const int* in_sizes, int n_in,
                              void* d_out, int out_size, void* d_ws, size_t ws_size,
                              hipStream_t stream) {
    const int*   tidx = (const int*)  d_in[0];
    const float* emb  = (const float*)d_in[1];
    const float* w1   = (const float*)d_in[2];
    const float* b1   = (const float*)d_in[3];
    const float* w2   = (const float*)d_in[4];
    const float* b2   = (const float*)d_in[5];
    const float* w3   = (const float*)d_in[6];
    const float* b3   = (const float*)d_in[7];
    const float* cb   = (const float*)d_in[8];
    const float* dw1  = (const float*)d_in[9];
    const float* db1  = (const float*)d_in[10];
    const float* dw2  = (const float*)d_in[11];
    const float* db2  = (const float*)d_in[12];
    const float* dw3  = (const float*)d_in[13];
    const float* db3  = (const float*)d_in[14];
    const float* ow   = (const float*)d_in[15];
    const float* ob   = (const float*)d_in[16];
    float* out = (float*)d_out;
    float* wp  = (float*)d_ws;                                   // f32 packs
    unsigned short* wph = (unsigned short*)((char*)d_ws + 122880); // bf16 packs
    float* part = (float*)((char*)d_ws + WS_LOSS_BYTES);         // [2048]

    prep_weights<<<292, 256, 0, stream>>>(w1, w2, w3, dw1, dw2, dw3, ow, wp, wph);
    vae_fused<<<NBATCH, 256, 0, stream>>>(tidx, emb, b1, b2, b3, cb,
                                          db1, db2, db3, ob, wp, wph,
                                          out, part);
    loss_final<<<1, 256, 0, stream>>>(part, out);
}